// Round 10
// baseline (321.172 us; speedup 1.0000x reference)
//
#include <hip/hip_runtime.h>
#include <stdint.h>

// logits = (mem^T @ x)/16 ; attn = softmax_M(logits) ; out = mem @ attn
// B=8, K=256, M=1024, N=4096.
// R10: NT=128 columns/block -> 512B-contiguous row chunks for the logits/out
// streams (chunk-contiguity is the only lever that has moved the write wall:
// 64B->1.03, 128B->1.14, 256B->1.5-1.9 TB/s). 256 blocks (1/CU), single round.
// GEMM2 in two m-half passes (attn half-tile 128KB in LDS).

typedef __attribute__((ext_vector_type(8))) __bf16 bf16x8;
typedef __attribute__((ext_vector_type(4))) float f32x4;

#define BQ 8
#define KD 256
#define MD 1024
#define ND 4096
#define NT 128

// LDS map (163840 B dynamic):
//   [0,64K):    x^T tile [n=128][k=256] bf16 (staging+GEMM1 only)
//   [0,132K):   per-wave transpose scratch, 16 x 8448B   (logits burst; out burst)
//   [0,128K):   attn half-tile [n=128][m=512] bf16       (GEMM2 passes)
//   [144K,152K): red_max   [152K,160K): red_sum          (dedicated, never aliased)
#define SCR_STRIDE 8448
#define SCR_ROW    528
#define RED_MAX_OFF 147456
#define RED_SUM_OFF 155648

__device__ __forceinline__ unsigned short bf16_rne(float f) {
    union { float f; uint32_t u; } c; c.f = f;
    uint32_t u = c.u;
    uint32_t r = (u + 0x7FFFu + ((u >> 16) & 1u)) >> 16;
    return (unsigned short)r;
}

// mem (f32 256x1024) -> mT bf16 [1024][256], mR bf16 [256][1024]
__global__ void prep_mem(const float* __restrict__ mem,
                         unsigned short* __restrict__ mT,
                         unsigned short* __restrict__ mR) {
    const int k = blockIdx.x;
    const int t = threadIdx.x;
    float4 v = reinterpret_cast<const float4*>(mem + (size_t)k * MD)[t];
    unsigned short h0 = bf16_rne(v.x), h1 = bf16_rne(v.y),
                   h2 = bf16_rne(v.z), h3 = bf16_rne(v.w);
    reinterpret_cast<uint2*>(mR + (size_t)k * MD)[t] =
        make_uint2((uint32_t)h0 | ((uint32_t)h1 << 16),
                   (uint32_t)h2 | ((uint32_t)h3 << 16));
    const int mm = t * 4;
    mT[(size_t)(mm + 0) * KD + k] = h0;
    mT[(size_t)(mm + 1) * KD + k] = h1;
    mT[(size_t)(mm + 2) * KD + k] = h2;
    mT[(size_t)(mm + 3) * KD + k] = h3;
}

__global__ __launch_bounds__(1024, 4) void fused_attn_mem(
    const float* __restrict__ x,
    const unsigned short* __restrict__ mT,
    const unsigned short* __restrict__ mR,
    float* __restrict__ out,
    float* __restrict__ logits)
{
    extern __shared__ char lds[];
    float* red_max = (float*)(lds + RED_MAX_OFF);   // [16 w][8 ct][16 col]
    float* red_sum = (float*)(lds + RED_SUM_OFF);

    const int tid = threadIdx.x;
    const int w   = tid >> 6;     // 0..15
    const int l   = tid & 63;
    const int l15 = l & 15;
    const int l4  = l >> 4;       // 0..3

    // 256 blocks: XCD g hosts strips [g*4, g*4+4) for all batches
    const int q   = blockIdx.x;
    const int g   = q & 7;
    const int j   = q >> 3;            // 0..31
    const int b   = j >> 2;            // 0..7
    const int sid = g * 4 + (j & 3);   // 0..31
    const int n0  = sid * NT;

    const float* xb = x + (size_t)b * KD * ND + n0;
    float* lg = logits + (size_t)b * MD * ND + n0;
    float* ob = out + (size_t)b * KD * ND + n0;

    // ---- stage x[b][:][n0:n0+128] -> LDS x^T [n][k] bf16, swizzled ----
    {
        const int k  = tid >> 2;         // 0..255
        const int nh = (tid & 3) * 32;   // 0,32,64,96
        const f32x4* src = reinterpret_cast<const f32x4*>(xb + (size_t)k * ND + nh);
        f32x4 v[8];
        #pragma unroll
        for (int i = 0; i < 8; ++i) v[i] = __builtin_nontemporal_load(src + i);
        #pragma unroll
        for (int jj = 0; jj < 32; ++jj) {
            const int n = nh + jj;
            const int off = n * 512 + (((k >> 3) ^ (n & 7)) << 4) + (k & 7) * 2;
            *(unsigned short*)(lds + off) = bf16_rne(v[jj >> 2][jj & 3]);
        }
    }
    __syncthreads();   // B1

    // ---- GEMM1: wave owns m-rows [w*64, w*64+64) x 128 n ----
    f32x4 acc[4][8];
    #pragma unroll
    for (int rt = 0; rt < 4; ++rt)
        #pragma unroll
        for (int ct = 0; ct < 8; ++ct)
            acc[rt][ct] = (f32x4){0.f, 0.f, 0.f, 0.f};

    #pragma unroll
    for (int ks = 0; ks < 8; ++ks) {
        const int kk = ks * 32 + l4 * 8;
        bf16x8 bfr[8];
        #pragma unroll
        for (int ct = 0; ct < 8; ++ct) {
            const int n = ct * 16 + l15;
            const int off = n * 512 + (((kk >> 3) ^ (n & 7)) << 4);
            bfr[ct] = *(const bf16x8*)(lds + off);
        }
        #pragma unroll
        for (int rt = 0; rt < 4; ++rt) {
            const int row = w * 64 + rt * 16 + l15;
            const bf16x8 afr = *(const bf16x8*)(mT + (size_t)row * KD + kk);
            #pragma unroll
            for (int ct = 0; ct < 8; ++ct)
                acc[rt][ct] = __builtin_amdgcn_mfma_f32_16x16x32_bf16(afr, bfr[ct], acc[rt][ct], 0, 0, 0);
        }
    }

    // ---- scale + per-column max + cross-wave reduce (before store burst) ----
    float lmax[8];
    #pragma unroll
    for (int ct = 0; ct < 8; ++ct) lmax[ct] = -3e38f;
    #pragma unroll
    for (int rt = 0; rt < 4; ++rt) {
        #pragma unroll
        for (int ct = 0; ct < 8; ++ct) {
            f32x4 v = acc[rt][ct] * 0.0625f;
            acc[rt][ct] = v;
            lmax[ct] = fmaxf(lmax[ct], fmaxf(fmaxf(v[0], v[1]), fmaxf(v[2], v[3])));
        }
    }
    #pragma unroll
    for (int ct = 0; ct < 8; ++ct) {
        float m = lmax[ct];
        m = fmaxf(m, __shfl_xor(m, 16, 64));
        m = fmaxf(m, __shfl_xor(m, 32, 64));
        lmax[ct] = m;
    }
    if (l < 16) {
        #pragma unroll
        for (int ct = 0; ct < 8; ++ct)
            red_max[(w * 8 + ct) * 16 + l] = lmax[ct];
    }
    __syncthreads();   // B2 (red region is dedicated; only fences red_max)

    float cmax[8];
    #pragma unroll
    for (int ct = 0; ct < 8; ++ct) {
        float m = -3e38f;
        #pragma unroll
        for (int ww = 0; ww < 16; ++ww)
            m = fmaxf(m, red_max[(ww * 8 + ct) * 16 + l15]);
        cmax[ct] = m;
    }

    // ---- logits: per-wave scratch transpose -> 512B-contiguous dwordx4 rows ----
    // x tile is dead (all waves past GEMM1 via B2); scratch [0,132K) is safe.
    {
        char* sw = lds + w * SCR_STRIDE;   // [16 m][132 dword] f32
        #pragma unroll
        for (int rt = 0; rt < 4; ++rt) {
            #pragma unroll
            for (int ct = 0; ct < 8; ++ct) {
                const int n = ct * 16 + l15;
                #pragma unroll
                for (int r = 0; r < 4; ++r) {
                    const int mloc = l4 * 4 + r;
                    *(float*)(sw + mloc * SCR_ROW + n * 4) = acc[rt][ct][r];
                }
            }
            __asm__ volatile("s_waitcnt lgkmcnt(0)" ::: "memory");
            __builtin_amdgcn_sched_barrier(0);
            #pragma unroll
            for (int p = 0; p < 8; ++p) {
                const int row = p * 2 + (l >> 5);
                const int c   = l & 31;
                const f32x4 v = *(const f32x4*)(sw + row * SCR_ROW + c * 16);
                *(f32x4*)(lg + (size_t)(w * 64 + rt * 16 + row) * ND + c * 4) = v;
            }
            __asm__ volatile("s_waitcnt lgkmcnt(0)" ::: "memory");
            __builtin_amdgcn_sched_barrier(0);
        }
    }

    // ---- p = exp(logit - cmax), per-column sum (drains stores in-shadow) ----
    float lsum[8];
    #pragma unroll
    for (int ct = 0; ct < 8; ++ct) lsum[ct] = 0.f;
    #pragma unroll
    for (int rt = 0; rt < 4; ++rt) {
        #pragma unroll
        for (int ct = 0; ct < 8; ++ct) {
            f32x4 v = acc[rt][ct];
            v[0] = __expf(v[0] - cmax[ct]);
            v[1] = __expf(v[1] - cmax[ct]);
            v[2] = __expf(v[2] - cmax[ct]);
            v[3] = __expf(v[3] - cmax[ct]);
            lsum[ct] += (v[0] + v[1]) + (v[2] + v[3]);
            acc[rt][ct] = v;
        }
    }
    #pragma unroll
    for (int ct = 0; ct < 8; ++ct) {
        float s = lsum[ct];
        s += __shfl_xor(s, 16, 64);
        s += __shfl_xor(s, 32, 64);
        lsum[ct] = s;
    }
    if (l < 16) {
        #pragma unroll
        for (int ct = 0; ct < 8; ++ct)
            red_sum[(w * 8 + ct) * 16 + l] = lsum[ct];
    }
    __syncthreads();   // B3 (also fences: all scratch reads done -> attn region safe)

    float rs[8];
    #pragma unroll
    for (int ct = 0; ct < 8; ++ct) {
        float s = 0.f;
        #pragma unroll
        for (int ww = 0; ww < 16; ++ww)
            s += red_sum[(ww * 8 + ct) * 16 + l15];
        rs[ct] = 1.0f / s;
    }

    // ---- GEMM2 in two m-half passes; attn half-tile [n=128][m=512] bf16 at [0,128K) ----
    f32x4 acc2[8];
    #pragma unroll
    for (int ct = 0; ct < 8; ++ct) acc2[ct] = (f32x4){0.f, 0.f, 0.f, 0.f};

    #pragma unroll
    for (int pass = 0; pass < 2; ++pass) {
        // waves owning m in [pass*512, pass*512+512) write their attn fragments
        if ((w >> 3) == pass) {
            #pragma unroll
            for (int rt = 0; rt < 4; ++rt) {
                #pragma unroll
                for (int ct = 0; ct < 8; ++ct) {
                    f32x4 v = acc[rt][ct];
                    unsigned short h0 = bf16_rne(v[0] * rs[ct]);
                    unsigned short h1 = bf16_rne(v[1] * rs[ct]);
                    unsigned short h2 = bf16_rne(v[2] * rs[ct]);
                    unsigned short h3 = bf16_rne(v[3] * rs[ct]);
                    const int mloc = (w & 7) * 64 + rt * 16 + l4 * 4;   // 0..511
                    const int n    = ct * 16 + l15;
                    const int off  = n * 1024 + (((mloc >> 3) ^ (n & 7)) << 4) + (mloc & 7) * 2;
                    *(uint2*)(lds + off) = make_uint2((uint32_t)h0 | ((uint32_t)h1 << 16),
                                                      (uint32_t)h2 | ((uint32_t)h3 << 16));
                }
            }
        }
        __syncthreads();   // B4/B6: attn half visible (and prior reads done)

        const unsigned short* arow = mR + (size_t)(w * 16 + l15) * MD + pass * 512;
        #pragma unroll 4
        for (int ks = 0; ks < 16; ++ks) {
            const int mk = ks * 32 + l4 * 8;   // local m in half
            const bf16x8 a2 = *(const bf16x8*)(arow + mk);
            #pragma unroll
            for (int ct = 0; ct < 8; ++ct) {
                const int n = ct * 16 + l15;
                const int off = n * 1024 + (((mk >> 3) ^ (n & 7)) << 4);
                const bf16x8 b2 = *(const bf16x8*)(lds + off);
                acc2[ct] = __builtin_amdgcn_mfma_f32_16x16x32_bf16(a2, b2, acc2[ct], 0, 0, 0);
            }
        }
        __syncthreads();   // B5/B7: half reads done; region reusable
    }

    // ---- out store via per-wave scratch transpose -> 512B-contiguous dwordx4 ----
    {
        char* sw = lds + w * SCR_STRIDE;
        #pragma unroll
        for (int ct = 0; ct < 8; ++ct) {
            const int n = ct * 16 + l15;
            #pragma unroll
            for (int r = 0; r < 4; ++r) {
                const int rr = l4 * 4 + r;
                *(float*)(sw + rr * SCR_ROW + n * 4) = acc2[ct][r];
            }
        }
        __asm__ volatile("s_waitcnt lgkmcnt(0)" ::: "memory");
        __builtin_amdgcn_sched_barrier(0);
        #pragma unroll
        for (int p = 0; p < 8; ++p) {
            const int row = p * 2 + (l >> 5);
            const int c   = l & 31;
            const f32x4 v = *(const f32x4*)(sw + row * SCR_ROW + c * 16);
            *(f32x4*)(ob + (size_t)(w * 16 + row) * ND + c * 4) = v;
        }
    }
}

extern "C" void kernel_launch(void* const* d_in, const int* in_sizes, int n_in,
                              void* d_out, int out_size, void* d_ws, size_t ws_size,
                              hipStream_t stream) {
    (void)in_sizes; (void)n_in; (void)out_size; (void)ws_size;
    const float* x   = (const float*)d_in[0];
    // d_in[1] (mask) is a forward no-op
    const float* mem = (const float*)d_in[2];

    float* out    = (float*)d_out;
    float* logits = (float*)d_out + (size_t)BQ * KD * ND;

    unsigned short* mT = (unsigned short*)d_ws;        // [1024][256] bf16
    unsigned short* mR = mT + (size_t)MD * KD;         // [256][1024] bf16

    static int lds_attr_set = 0;
    if (!lds_attr_set) {
        (void)hipFuncSetAttribute(reinterpret_cast<const void*>(&fused_attn_mem),
                                  hipFuncAttributeMaxDynamicSharedMemorySize, 163840);
        lds_attr_set = 1;
    }

    prep_mem<<<dim3(256), dim3(256), 0, stream>>>(mem, mT, mR);
    fused_attn_mem<<<dim3(BQ * (ND / NT)), dim3(1024), 163840, stream>>>(x, mT, mR, out, logits);
}